// Round 6
// baseline (259.939 us; speedup 1.0000x reference)
//
#include <hip/hip_runtime.h>
#include <math.h>

typedef unsigned short u16;
typedef unsigned short u16x8 __attribute__((ext_vector_type(8)));
typedef __bf16 bf16v8 __attribute__((ext_vector_type(8)));
typedef float f32x4 __attribute__((ext_vector_type(4)));

static __device__ __forceinline__ float b2f(u16 u){ union{unsigned v; float f;} x; x.v=((unsigned)u)<<16; return x.f; }
static __device__ __forceinline__ u16 f2b(float f){ union{float f; unsigned v;} x; x.f=f; unsigned r=x.v+0x7fffu+((x.v>>16)&1u); return (u16)(r>>16); }
static __device__ __forceinline__ f32x4 mfma16(bf16v8 a, bf16v8 b, f32x4 c){
  return __builtin_amdgcn_mfma_f32_16x16x32_bf16(a,b,c,0,0,0);
}
#define GLDS16(g,l) __builtin_amdgcn_global_load_lds((const __attribute__((address_space(1))) unsigned*)(g), (__attribute__((address_space(3))) unsigned*)(l), 16, 0, 0)

// ---------------- convert f32 -> bf16 ----------------
__global__ __launch_bounds__(256) void convert_k(const float* __restrict__ src, u16* __restrict__ dst, int n8){
  int i = blockIdx.x*256 + threadIdx.x;
  if (i >= n8) return;
  const float* s = src + (size_t)i*8;
  f32x4 a = *(const f32x4*)s, b = *(const f32x4*)(s+4);
  u16x8 o;
  #pragma unroll
  for (int j=0;j<4;++j){ o[j] = f2b(a[j]); o[j+4] = f2b(b[j]); }
  *(u16x8*)(dst + (size_t)i*8) = o;
}

// ---------------- weight transpose: f32 in [R][C] -> bf16 out [C][R] ----------------
__global__ __launch_bounds__(256) void transpose_k(const float* __restrict__ in, u16* __restrict__ out, int R, int C){
  __shared__ u16 tile[64][66];
  int ct = C >> 6;
  int bx = blockIdx.x % ct, by = blockIdx.x / ct;
  int t = threadIdx.x;
  #pragma unroll
  for (int it=0; it<16; ++it){
    int idx = it*256 + t; int r = idx>>6, c = idx&63;
    tile[r][c] = f2b(in[(size_t)(by*64+r)*C + bx*64 + c]);
  }
  __syncthreads();
  #pragma unroll
  for (int it=0; it<16; ++it){
    int idx = it*256 + t; int c = idx>>6, r = idx&63;
    out[(size_t)(bx*64+c)*R + by*64 + r] = tile[r][c];
  }
}

// ---------------- rmsnorm: f32 in, f32 gamma, bf16 out ----------------
__global__ __launch_bounds__(256) void rmsn_k(const float* __restrict__ x, const float* __restrict__ g, u16* __restrict__ o){
  int w = threadIdx.x>>6, l = threadIdx.x&63;
  size_t row = (size_t)blockIdx.x*4 + w;
  const float* xr = x + row*512 + l*8;
  f32x4 a = *(const f32x4*)xr, b = *(const f32x4*)(xr+4);
  float f[8]; float ss = 0.f;
  #pragma unroll
  for (int j=0;j<4;++j){ f[j]=a[j]; f[j+4]=b[j]; }
  #pragma unroll
  for (int j=0;j<8;++j) ss += f[j]*f[j];
  #pragma unroll
  for (int m=1;m<64;m<<=1) ss += __shfl_xor(ss, m, 64);
  float inv = rsqrtf(ss*(1.0f/512.f) + 1e-6f);
  f32x4 ga = *(const f32x4*)(g + l*8), gb = *(const f32x4*)(g + l*8 + 4);
  u16x8 ov;
  #pragma unroll
  for (int j=0;j<4;++j){ ov[j] = f2b(f[j]*inv*(1.f + ga[j])); ov[j+4] = f2b(f[j+4]*inv*(1.f + gb[j])); }
  *(u16x8*)(o + row*512 + l*8) = ov;
}

// ---------------- GEMM: C[M,N] = A[M,K] @ BT[N,K]^T + bias, epilogues ----------------
template<int BN, int EPI, bool CONCAT>
__global__ __launch_bounds__(256,2) void gemm_k(
  const u16* __restrict__ A, const u16* __restrict__ Avk, const u16* __restrict__ Avv,
  const u16* __restrict__ BT, const float* __restrict__ bias,
  u16* __restrict__ Cb, float* __restrict__ Cf,
  const float* __restrict__ resid, const float* __restrict__ addf,
  int M, int N, int K)
{
  constexpr int BM = 128, BK = 64;
  constexpr int NFR = BN/32;
  __shared__ alignas(16) u16 sm[(BM+BN)*BK];
  u16* As = sm; u16* Bs = sm + BM*BK;
  const int t = threadIdx.x, w = t>>6, l = t&63, grp = l>>4, l16 = l&15;
  const int wr = w>>1, wc = w&1;
  const int m0 = blockIdx.y*BM, n0 = blockIdx.x*BN;

  f32x4 acc[4][NFR];
  #pragma unroll
  for (int m=0;m<4;++m)
    #pragma unroll
    for (int n=0;n<NFR;++n) acc[m][n] = f32x4{0.f,0.f,0.f,0.f};

  for (int k0 = 0; k0 < K; k0 += BK){
    #pragma unroll
    for (int it=0; it<4; ++it){
      int p16 = it*256 + t;
      int row = p16>>3; int offb = (p16&7)<<4;
      int swz = offb ^ ((row&7)<<4);
      const u16* src;
      if (CONCAT){
        int g = m0+row, bb = g>>10, ii = g&1023;
        const u16* base = (ii < 512) ? (Avk + (size_t)(bb*512+ii)*4096)
                                     : (Avv + (size_t)(bb*512+ii-512)*4096);
        src = base + k0 + (swz>>1);
      } else {
        src = A + (size_t)(m0+row)*K + k0 + (swz>>1);
      }
      GLDS16(src, As + (it*256 + w*64)*8);
    }
    #pragma unroll
    for (int it=0; it<NFR; ++it){
      int p16 = it*256 + t;
      int row = p16>>3; int offb = (p16&7)<<4;
      int swz = offb ^ ((row&7)<<4);
      const u16* src = BT + (size_t)(n0+row)*K + k0 + (swz>>1);
      GLDS16(src, Bs + (it*256 + w*64)*8);
    }
    __syncthreads();

    bf16v8 af[4][2], bfr[NFR][2];
    #pragma unroll
    for (int kk=0;kk<2;++kk){
      #pragma unroll
      for (int m=0;m<4;++m){
        int row = wr*64 + m*16 + l16;
        int offb = (kk*64 + grp*16) ^ ((row&7)<<4);
        af[m][kk] = *(const bf16v8*)((const char*)As + row*128 + offb);
      }
      #pragma unroll
      for (int n=0;n<NFR;++n){
        int row = wc*(BN/2) + n*16 + l16;
        int offb = (kk*64 + grp*16) ^ ((row&7)<<4);
        bfr[n][kk] = *(const bf16v8*)((const char*)Bs + row*128 + offb);
      }
    }
    #pragma unroll
    for (int kk=0;kk<2;++kk)
      #pragma unroll
      for (int m=0;m<4;++m)
        #pragma unroll
        for (int n=0;n<NFR;++n)
          acc[m][n] = mfma16(af[m][kk], bfr[n][kk], acc[m][n]);
    __syncthreads();
  }

  bool unused = false; (void)unused;
  #pragma unroll
  for (int m=0;m<4;++m){
    #pragma unroll
    for (int n=0;n<NFR;++n){
      #pragma unroll
      for (int r=0;r<4;++r){
        int row = m0 + wr*64 + m*16 + grp*4 + r;
        int col = n0 + wc*(BN/2) + n*16 + l16;
        size_t idx = (size_t)row*N + col;
        float v = acc[m][n][r] + bias[col];
        if (EPI == 0){
          Cb[idx] = f2b(v);
        } else if (EPI == 1){
          Cf[idx] = v + resid[idx];
        } else if (EPI == 2){
          v = 0.5f*v*(1.f + erff(v*0.70710678f));
          Cb[idx] = f2b(v);
        } else {
          Cf[idx] = v + addf[idx];
        }
      }
    }
  }
}

// ---------------- scatter q/k with rope (q pre-scaled by 1/8); copy sk into KEYS ----------------
__global__ __launch_bounds__(256) void scatter_qk(const u16* __restrict__ qkv, const u16* __restrict__ skv,
                                                  u16* __restrict__ Qh, u16* __restrict__ KEYS){
  int bi = blockIdx.x;             // row = b*1024 + i
  int b = bi>>10, i = bi&1023;
  int t = threadIdx.x;
  int h = t>>5, dp = t&31;
  const u16* qrow = qkv + (size_t)bi*1536;
  float invf = __expf(-(float)dp * (9.2103403720f/32.f));  // 10000^(-dp/32)
  float fr = (float)i * invf;
  float sn, cs; __sincosf(fr, &sn, &cs);
  int bh = b*8 + h;
  // q (scaled by 1/8 = softmax scale)
  float x1 = b2f(qrow[h*64+dp]), x2 = b2f(qrow[h*64+dp+32]);
  u16* qd = Qh + ((size_t)bh*1024 + i)*64;
  qd[dp]    = f2b((x1*cs - x2*sn)*0.125f);
  qd[dp+32] = f2b((x2*cs + x1*sn)*0.125f);
  // k -> KEYS rows [512 + i]
  x1 = b2f(qrow[512+h*64+dp]); x2 = b2f(qrow[512+h*64+dp+32]);
  u16* kd = KEYS + ((size_t)bh*1536 + 512 + i)*64;
  kd[dp]    = f2b(x1*cs - x2*sn);
  kd[dp+32] = f2b(x2*cs + x1*sn);
  // sk copy (no rope) -> KEYS rows [0..511]
  if (i < 512){
    const u16* skrow = skv + ((size_t)b*1024 + i)*512;
    for (int e = t; e < 512; e += 256){
      int hh = e>>6, d = e&63;
      KEYS[((size_t)(b*8+hh)*1536 + i)*64 + d] = skrow[e];
    }
  }
}

// ---------------- build transposed values VT[bh][d][j] ----------------
__global__ __launch_bounds__(256) void build_vt(const u16* __restrict__ qkv, const u16* __restrict__ skv,
                                                u16* __restrict__ VT){
  __shared__ u16 tile[64][66];
  int blk = blockIdx.x;
  int bh = blk / 24, tt = blk % 24;
  int b = bh>>3, h = bh&7;
  int t = threadIdx.x;
  int jbase;
  if (tt < 16){
    int i0 = tt*64; jbase = 512 + i0;
    #pragma unroll
    for (int it=0; it<16; ++it){
      int idx = it*256+t; int r = idx>>6, c = idx&63;
      tile[r][c] = qkv[((size_t)b*1024 + i0 + r)*1536 + 1024 + h*64 + c];
    }
  } else {
    int j0 = (tt-16)*64; jbase = j0;
    #pragma unroll
    for (int it=0; it<16; ++it){
      int idx = it*256+t; int r = idx>>6, c = idx&63;
      tile[r][c] = skv[((size_t)b*1024 + 512 + j0 + r)*512 + h*64 + c];
    }
  }
  __syncthreads();
  #pragma unroll
  for (int it=0; it<16; ++it){
    int idx = it*256+t; int c = idx>>6, r = idx&63;
    VT[((size_t)bh*64 + c)*1536 + jbase + r] = tile[r][c];
  }
}

// ---------------- flash attention, swapped QK^T (lane-local softmax), 3 causal KV-splits ----------------
// grid: 1536 = bh(32) * qgroup(16 of 64 rows) * split(3); 4 waves, each 16 q-rows.
// Swapped MFMA: St = K·Q^T so lane (grp,l16) holds 16 tile-scores for q-row i0+l16.
__global__ __launch_bounds__(256,2) void attn_k(const u16* __restrict__ Qh, const u16* __restrict__ KEYS,
                                                const u16* __restrict__ VT,
                                                float* __restrict__ Op, float2* __restrict__ Ml2){
  __shared__ alignas(16) u16 Pl[4][16*64];      // 2KB/wave: 16 q-rows x 128B, XOR-swizzled
  const int t = threadIdx.x, w = t>>6, l = t&63, grp = l>>4, l16 = l&15;
  const int blk = blockIdx.x;
  const int s = blk % 3, qg = (blk/3) & 15, bh = blk/48;
  const int i0 = qg*64 + w*16;
  const int klo = s*512;
  int khi = i0 + 528; { int cap = klo + 512; if (khi > cap) khi = cap; }
  const size_t prow = ((size_t)s*32 + bh)*1024;

  if (khi <= klo){
    if (l < 16) Ml2[prow + i0 + l] = make_float2(-1e30f, 0.f);
    return;
  }

  const u16* Qb = Qh + (size_t)bh*65536;
  const u16* Kb = KEYS + (size_t)bh*98304;
  const u16* Vb = VT + (size_t)bh*98304;
  u16* Pw = &Pl[w][0];
  const int swz = (l16&7)<<4;
  const int qlim = i0 + l16 + 512;              // this lane's causal bound (key <= qlim)

  bf16v8 qf[2];
  #pragma unroll
  for (int kk=0;kk<2;++kk)
    qf[kk] = *(const bf16v8*)(Qb + (size_t)(i0 + l16)*64 + kk*32 + grp*8);

  f32x4 Ot[4];                                   // O^T: reg r -> d = n*16+grp*4+r, col q = l16
  #pragma unroll
  for (int n=0;n<4;++n) Ot[n] = f32x4{0.f,0.f,0.f,0.f};
  float mrun = -1e30f, lrun = 0.f;

  for (int j0 = klo; j0 < khi; j0 += 64){
    f32x4 St[4];
    #pragma unroll
    for (int n=0;n<4;++n) St[n] = f32x4{0.f,0.f,0.f,0.f};
    #pragma unroll
    for (int kk=0;kk<2;++kk)
      #pragma unroll
      for (int n=0;n<4;++n){
        bf16v8 kf = *(const bf16v8*)(Kb + (size_t)(j0 + n*16 + l16)*64 + kk*32 + grp*8);
        St[n] = mfma16(kf, qf[kk], St[n]);       // swapped: row=key(grp*4+r), col=q(l16)
      }
    const bool tail = (j0 + 63 > i0 + 512);
    float sv[4][4]; float m_loc = -1e30f;
    #pragma unroll
    for (int n=0;n<4;++n)
      #pragma unroll
      for (int r=0;r<4;++r){
        float x = St[n][r];                      // scale folded into Q
        if (tail && (j0 + n*16 + grp*4 + r > qlim)) x = -1e30f;
        sv[n][r] = x; m_loc = fmaxf(m_loc, x);
      }
    m_loc = fmaxf(m_loc, __shfl_xor(m_loc, 16, 64));
    m_loc = fmaxf(m_loc, __shfl_xor(m_loc, 32, 64));
    float mnew = fmaxf(mrun, m_loc);
    float alpha = __expf(mrun - mnew);
    float rs = 0.f;
    unsigned pk[8];
    #pragma unroll
    for (int n=0;n<4;++n)
      #pragma unroll
      for (int c=0;c<2;++c){
        float p0 = __expf(sv[n][2*c]   - mnew);
        float p1 = __expf(sv[n][2*c+1] - mnew);
        rs += p0 + p1;
        pk[n*2+c] = (unsigned)f2b(p0) | ((unsigned)f2b(p1) << 16);
      }
    rs += __shfl_xor(rs, 16, 64);
    rs += __shfl_xor(rs, 32, 64);
    lrun = lrun*alpha + rs;
    mrun = mnew;
    #pragma unroll
    for (int n=0;n<4;++n)
      #pragma unroll
      for (int r=0;r<4;++r) Ot[n][r] *= alpha;
    // P^T -> LDS (bf16 pairs), row q=l16, swizzled; keys n*16+grp*4+2c+{0,1} -> byte n*32+grp*8+c*4
    #pragma unroll
    for (int n=0;n<4;++n)
      #pragma unroll
      for (int c=0;c<2;++c)
        *(unsigned*)((char*)Pw + l16*128 + ((n*32 + grp*8 + c*4) ^ swz)) = pk[n*2+c];
    asm volatile("s_waitcnt lgkmcnt(0)" ::: "memory");   // wave-local: writes visible to own wave's reads
    bf16v8 pb0 = *(const bf16v8*)((const char*)Pw + l16*128 + ((grp*16)      ^ swz));
    bf16v8 pb1 = *(const bf16v8*)((const char*)Pw + l16*128 + ((64 + grp*16) ^ swz));
    #pragma unroll
    for (int n=0;n<4;++n){
      bf16v8 vf0 = *(const bf16v8*)(Vb + (size_t)(n*16 + l16)*1536 + j0 +      grp*8);
      bf16v8 vf1 = *(const bf16v8*)(Vb + (size_t)(n*16 + l16)*1536 + j0 + 32 + grp*8);
      Ot[n] = mfma16(vf0, pb0, Ot[n]);
      Ot[n] = mfma16(vf1, pb1, Ot[n]);
    }
  }

  // transpose O^T -> Op[q][d] via per-wave LDS (two 32-d halves), then store
  float* Tw = (float*)Pw;
  #pragma unroll
  for (int hf=0; hf<2; ++hf){
    #pragma unroll
    for (int nn=0; nn<2; ++nn)
      #pragma unroll
      for (int r=0; r<4; ++r)
        *(float*)((char*)Tw + l16*128 + ((((nn*16 + grp*4 + r)*4)) ^ swz)) = Ot[hf*2+nn][r];
    asm volatile("s_waitcnt lgkmcnt(0)" ::: "memory");
    f32x4 v0 = *(const f32x4*)((const char*)Tw + l16*128 + ((grp*32)      ^ swz));
    f32x4 v1 = *(const f32x4*)((const char*)Tw + l16*128 + ((grp*32 + 16) ^ swz));
    float* dst = Op + (prow + i0 + l16)*64 + hf*32 + grp*8;
    *(f32x4*)dst = v0;
    *(f32x4*)(dst+4) = v1;
    asm volatile("s_waitcnt lgkmcnt(0)" ::: "memory");
  }
  if (grp == 0) Ml2[prow + i0 + l16] = make_float2(mrun, lrun);
}

// ---------------- combine 3 KV-split partials -> AO bf16 ----------------
__global__ __launch_bounds__(256) void attn_combine(const float* __restrict__ Op, const float2* __restrict__ Ml2,
                                                    u16* __restrict__ AO){
  int bi = blockIdx.x;                 // b*1024 + i
  int b = bi>>10, i = bi&1023;
  int t = threadIdx.x; int h = t>>6, d = t&63;
  int bh = b*8 + h;
  float2 ml[3]; float M = -1e30f;
  #pragma unroll
  for (int s=0;s<3;++s){ ml[s] = Ml2[((size_t)s*32 + bh)*1024 + i]; M = fmaxf(M, ml[s].x); }
  float denom = 0.f, o = 0.f;
  #pragma unroll
  for (int s=0;s<3;++s){
    if (ml[s].y > 0.f){
      float a = __expf(ml[s].x - M);
      denom += a * ml[s].y;
      o += a * Op[(((size_t)s*32 + bh)*1024 + i)*64 + d];
    }
  }
  AO[((size_t)b*1024 + i)*512 + h*64 + d] = f2b(o / denom);
}

// ---------------- launcher ----------------
extern "C" void kernel_launch(void* const* d_in, const int* in_sizes, int n_in,
                              void* d_out, int out_size, void* d_ws, size_t ws_size,
                              hipStream_t stream) {
  const float* planning = (const float*)d_in[0];
  const float* vk   = (const float*)d_in[1];
  const float* vv   = (const float*)d_in[2];
  const float* Wskv = (const float*)d_in[3];
  const float* bskv = (const float*)d_in[4];
  const float* Wqkv = (const float*)d_in[5];
  const float* bqkv = (const float*)d_in[6];
  const float* Wout = (const float*)d_in[7];
  const float* bout = (const float*)d_in[8];
  const float* Wff1 = (const float*)d_in[9];
  const float* bff1 = (const float*)d_in[10];
  const float* Wff2 = (const float*)d_in[11];
  const float* bff2 = (const float*)d_in[12];
  const float* g1   = (const float*)d_in[13];
  const float* g2   = (const float*)d_in[14];
  float* outp = (float*)d_out;

  char* w8 = (char*)d_ws;
  size_t off = 0;
  auto take = [&](size_t n)->char*{ char* p = w8 + off; off += (n + 255) & ~(size_t)255; return p; };
  u16* vkc     = (u16*)take((size_t)4*512*4096*2);
  u16* vvc     = (u16*)take((size_t)4*512*4096*2);
  u16* WTqkv   = (u16*)take((size_t)1536*512*2);
  u16* WTskv   = (u16*)take((size_t)512*4096*2);
  u16* WTout   = (u16*)take((size_t)512*512*2);
  u16* WTff1   = (u16*)take((size_t)512*512*2);
  u16* WTff2   = (u16*)take((size_t)512*512*2);
  u16* normed1 = (u16*)take((size_t)4096*512*2);
  u16* qkv     = (u16*)take((size_t)4096*1536*2);
  u16* skv     = (u16*)take((size_t)4096*512*2);
  u16* Qh      = (u16*)take((size_t)32*1024*64*2);
  u16* KEYS    = (u16*)take((size_t)32*1536*64*2);
  u16* VT      = (u16*)take((size_t)32*64*1536*2);
  u16* AO      = (u16*)take((size_t)4096*512*2);
  float* all_out = (float*)take((size_t)4096*512*4);
  u16* normed2 = (u16*)take((size_t)4096*512*2);
  u16* h1      = (u16*)take((size_t)4096*512*2);
  float* Op    = (float*)take((size_t)3*32*1024*64*4);
  float2* Ml2  = (float2*)take((size_t)3*32*1024*8);
  (void)in_sizes; (void)n_in; (void)out_size; (void)ws_size;

  convert_k<<<dim3(4096), 256, 0, stream>>>(vk, vkc, 1048576);
  convert_k<<<dim3(4096), 256, 0, stream>>>(vv, vvc, 1048576);

  transpose_k<<<dim3(192), 256, 0, stream>>>(Wqkv, WTqkv, 512, 1536);
  transpose_k<<<dim3(512), 256, 0, stream>>>(Wskv, WTskv, 4096, 512);
  transpose_k<<<dim3(64),  256, 0, stream>>>(Wout, WTout, 512, 512);
  transpose_k<<<dim3(64),  256, 0, stream>>>(Wff1, WTff1, 512, 512);
  transpose_k<<<dim3(64),  256, 0, stream>>>(Wff2, WTff2, 512, 512);
  rmsn_k<<<dim3(1024), 256, 0, stream>>>(planning, g1, normed1);

  gemm_k<128,0,false><<<dim3(12,32), 256, 0, stream>>>(normed1,nullptr,nullptr, WTqkv, bqkv, qkv, nullptr, nullptr, nullptr, 4096, 1536, 512);
  gemm_k<64,0,true ><<<dim3(8,32),  256, 0, stream>>>(nullptr, vkc, vvc,       WTskv, bskv, skv, nullptr, nullptr, nullptr, 4096, 512, 4096);

  scatter_qk<<<dim3(4096), 256, 0, stream>>>(qkv, skv, Qh, KEYS);
  build_vt<<<dim3(768), 256, 0, stream>>>(qkv, skv, VT);

  attn_k<<<dim3(1536), 256, 0, stream>>>(Qh, KEYS, VT, Op, Ml2);
  attn_combine<<<dim3(4096), 256, 0, stream>>>(Op, Ml2, AO);

  gemm_k<64,1,false><<<dim3(8,32), 256, 0, stream>>>(AO, nullptr,nullptr, WTout, bout, nullptr, all_out, planning, nullptr, 4096, 512, 512);
  rmsn_k<<<dim3(1024), 256, 0, stream>>>(all_out, g2, normed2);
  gemm_k<64,2,false><<<dim3(8,32), 256, 0, stream>>>(normed2, nullptr,nullptr, WTff1, bff1, h1, nullptr, nullptr, nullptr, 4096, 512, 512);
  gemm_k<64,3,false><<<dim3(8,32), 256, 0, stream>>>(h1, nullptr,nullptr, WTff2, bff2, nullptr, outp, nullptr, all_out, 4096, 512, 512);
}

// Round 7
// 204.176 us; speedup vs baseline: 1.2731x; 1.2731x over previous
//
#include <hip/hip_runtime.h>
#include <math.h>

typedef unsigned short u16;
typedef unsigned short u16x8 __attribute__((ext_vector_type(8)));
typedef __bf16 bf16v8 __attribute__((ext_vector_type(8)));
typedef float f32x4 __attribute__((ext_vector_type(4)));

static __device__ __forceinline__ float b2f(u16 u){ union{unsigned v; float f;} x; x.v=((unsigned)u)<<16; return x.f; }
static __device__ __forceinline__ u16 f2b(float f){ union{float f; unsigned v;} x; x.f=f; unsigned r=x.v+0x7fffu+((x.v>>16)&1u); return (u16)(r>>16); }
static __device__ __forceinline__ f32x4 mfma16(bf16v8 a, bf16v8 b, f32x4 c){
  return __builtin_amdgcn_mfma_f32_16x16x32_bf16(a,b,c,0,0,0);
}
#define GLDS16(g,l) __builtin_amdgcn_global_load_lds((const __attribute__((address_space(1))) unsigned*)(g), (__attribute__((address_space(3))) unsigned*)(l), 16, 0, 0)

// ---------------- convert f32 -> bf16 ----------------
__global__ __launch_bounds__(256) void convert_k(const float* __restrict__ src, u16* __restrict__ dst, int n8){
  int i = blockIdx.x*256 + threadIdx.x;
  if (i >= n8) return;
  const float* s = src + (size_t)i*8;
  f32x4 a = *(const f32x4*)s, b = *(const f32x4*)(s+4);
  u16x8 o;
  #pragma unroll
  for (int j=0;j<4;++j){ o[j] = f2b(a[j]); o[j+4] = f2b(b[j]); }
  *(u16x8*)(dst + (size_t)i*8) = o;
}

// ---------------- weight transpose: f32 in [R][C] -> bf16 out [C][R] ----------------
__global__ __launch_bounds__(256) void transpose_k(const float* __restrict__ in, u16* __restrict__ out, int R, int C){
  __shared__ u16 tile[64][66];
  int ct = C >> 6;
  int bx = blockIdx.x % ct, by = blockIdx.x / ct;
  int t = threadIdx.x;
  #pragma unroll
  for (int it=0; it<16; ++it){
    int idx = it*256 + t; int r = idx>>6, c = idx&63;
    tile[r][c] = f2b(in[(size_t)(by*64+r)*C + bx*64 + c]);
  }
  __syncthreads();
  #pragma unroll
  for (int it=0; it<16; ++it){
    int idx = it*256 + t; int c = idx>>6, r = idx&63;
    out[(size_t)(bx*64+c)*R + by*64 + r] = tile[r][c];
  }
}

// ---------------- rmsnorm: f32 in, f32 gamma, bf16 out ----------------
__global__ __launch_bounds__(256) void rmsn_k(const float* __restrict__ x, const float* __restrict__ g, u16* __restrict__ o){
  int w = threadIdx.x>>6, l = threadIdx.x&63;
  size_t row = (size_t)blockIdx.x*4 + w;
  const float* xr = x + row*512 + l*8;
  f32x4 a = *(const f32x4*)xr, b = *(const f32x4*)(xr+4);
  float f[8]; float ss = 0.f;
  #pragma unroll
  for (int j=0;j<4;++j){ f[j]=a[j]; f[j+4]=b[j]; }
  #pragma unroll
  for (int j=0;j<8;++j) ss += f[j]*f[j];
  #pragma unroll
  for (int m=1;m<64;m<<=1) ss += __shfl_xor(ss, m, 64);
  float inv = rsqrtf(ss*(1.0f/512.f) + 1e-6f);
  f32x4 ga = *(const f32x4*)(g + l*8), gb = *(const f32x4*)(g + l*8 + 4);
  u16x8 ov;
  #pragma unroll
  for (int j=0;j<4;++j){ ov[j] = f2b(f[j]*inv*(1.f + ga[j])); ov[j+4] = f2b(f[j+4]*inv*(1.f + gb[j])); }
  *(u16x8*)(o + row*512 + l*8) = ov;
}

// ---------------- GEMM: C[M,N] = A[M,K] @ BT[N,K]^T + bias, epilogues ----------------
template<int BN, int EPI, bool CONCAT>
__global__ __launch_bounds__(256,2) void gemm_k(
  const u16* __restrict__ A, const u16* __restrict__ Avk, const u16* __restrict__ Avv,
  const u16* __restrict__ BT, const float* __restrict__ bias,
  u16* __restrict__ Cb, float* __restrict__ Cf,
  const float* __restrict__ resid, const float* __restrict__ addf,
  int M, int N, int K)
{
  constexpr int BM = 128, BK = 64;
  constexpr int NFR = BN/32;
  __shared__ alignas(16) u16 sm[(BM+BN)*BK];
  u16* As = sm; u16* Bs = sm + BM*BK;
  const int t = threadIdx.x, w = t>>6, l = t&63, grp = l>>4, l16 = l&15;
  const int wr = w>>1, wc = w&1;
  const int m0 = blockIdx.y*BM, n0 = blockIdx.x*BN;

  f32x4 acc[4][NFR];
  #pragma unroll
  for (int m=0;m<4;++m)
    #pragma unroll
    for (int n=0;n<NFR;++n) acc[m][n] = f32x4{0.f,0.f,0.f,0.f};

  for (int k0 = 0; k0 < K; k0 += BK){
    #pragma unroll
    for (int it=0; it<4; ++it){
      int p16 = it*256 + t;
      int row = p16>>3; int offb = (p16&7)<<4;
      int swz = offb ^ ((row&7)<<4);
      const u16* src;
      if (CONCAT){
        int g = m0+row, bb = g>>10, ii = g&1023;
        const u16* base = (ii < 512) ? (Avk + (size_t)(bb*512+ii)*4096)
                                     : (Avv + (size_t)(bb*512+ii-512)*4096);
        src = base + k0 + (swz>>1);
      } else {
        src = A + (size_t)(m0+row)*K + k0 + (swz>>1);
      }
      GLDS16(src, As + (it*256 + w*64)*8);
    }
    #pragma unroll
    for (int it=0; it<NFR; ++it){
      int p16 = it*256 + t;
      int row = p16>>3; int offb = (p16&7)<<4;
      int swz = offb ^ ((row&7)<<4);
      const u16* src = BT + (size_t)(n0+row)*K + k0 + (swz>>1);
      GLDS16(src, Bs + (it*256 + w*64)*8);
    }
    __syncthreads();

    bf16v8 af[4][2], bfr[NFR][2];
    #pragma unroll
    for (int kk=0;kk<2;++kk){
      #pragma unroll
      for (int m=0;m<4;++m){
        int row = wr*64 + m*16 + l16;
        int offb = (kk*64 + grp*16) ^ ((row&7)<<4);
        af[m][kk] = *(const bf16v8*)((const char*)As + row*128 + offb);
      }
      #pragma unroll
      for (int n=0;n<NFR;++n){
        int row = wc*(BN/2) + n*16 + l16;
        int offb = (kk*64 + grp*16) ^ ((row&7)<<4);
        bfr[n][kk] = *(const bf16v8*)((const char*)Bs + row*128 + offb);
      }
    }
    #pragma unroll
    for (int kk=0;kk<2;++kk)
      #pragma unroll
      for (int m=0;m<4;++m)
        #pragma unroll
        for (int n=0;n<NFR;++n)
          acc[m][n] = mfma16(af[m][kk], bfr[n][kk], acc[m][n]);
    __syncthreads();
  }

  #pragma unroll
  for (int m=0;m<4;++m){
    #pragma unroll
    for (int n=0;n<NFR;++n){
      #pragma unroll
      for (int r=0;r<4;++r){
        int row = m0 + wr*64 + m*16 + grp*4 + r;
        int col = n0 + wc*(BN/2) + n*16 + l16;
        size_t idx = (size_t)row*N + col;
        float v = acc[m][n][r] + bias[col];
        if (EPI == 0){
          Cb[idx] = f2b(v);
        } else if (EPI == 1){
          Cf[idx] = v + resid[idx];
        } else if (EPI == 2){
          v = 0.5f*v*(1.f + erff(v*0.70710678f));
          Cb[idx] = f2b(v);
        } else {
          Cf[idx] = v + addf[idx];
        }
      }
    }
  }
}

// ---------------- scatter q/k with rope (q pre-scaled by 1/8); copy sk into KEYS ----------------
__global__ __launch_bounds__(256) void scatter_qk(const u16* __restrict__ qkv, const u16* __restrict__ skv,
                                                  u16* __restrict__ Qh, u16* __restrict__ KEYS){
  int bi = blockIdx.x;             // row = b*1024 + i
  int b = bi>>10, i = bi&1023;
  int t = threadIdx.x;
  int h = t>>5, dp = t&31;
  const u16* qrow = qkv + (size_t)bi*1536;
  float invf = __expf(-(float)dp * (9.2103403720f/32.f));  // 10000^(-dp/32)
  float fr = (float)i * invf;
  float sn, cs; __sincosf(fr, &sn, &cs);
  int bh = b*8 + h;
  float x1 = b2f(qrow[h*64+dp]), x2 = b2f(qrow[h*64+dp+32]);
  u16* qd = Qh + ((size_t)bh*1024 + i)*64;
  qd[dp]    = f2b((x1*cs - x2*sn)*0.125f);
  qd[dp+32] = f2b((x2*cs + x1*sn)*0.125f);
  x1 = b2f(qrow[512+h*64+dp]); x2 = b2f(qrow[512+h*64+dp+32]);
  u16* kd = KEYS + ((size_t)bh*1536 + 512 + i)*64;
  kd[dp]    = f2b(x1*cs - x2*sn);
  kd[dp+32] = f2b(x2*cs + x1*sn);
  if (i < 512){
    const u16* skrow = skv + ((size_t)b*1024 + i)*512;
    for (int e = t; e < 512; e += 256){
      int hh = e>>6, d = e&63;
      KEYS[((size_t)(b*8+hh)*1536 + i)*64 + d] = skrow[e];
    }
  }
}

// ---------------- build transposed values VT[bh][d][j] ----------------
__global__ __launch_bounds__(256) void build_vt(const u16* __restrict__ qkv, const u16* __restrict__ skv,
                                                u16* __restrict__ VT){
  __shared__ u16 tile[64][66];
  int blk = blockIdx.x;
  int bh = blk / 24, tt = blk % 24;
  int b = bh>>3, h = bh&7;
  int t = threadIdx.x;
  int jbase;
  if (tt < 16){
    int i0 = tt*64; jbase = 512 + i0;
    #pragma unroll
    for (int it=0; it<16; ++it){
      int idx = it*256+t; int r = idx>>6, c = idx&63;
      tile[r][c] = qkv[((size_t)b*1024 + i0 + r)*1536 + 1024 + h*64 + c];
    }
  } else {
    int j0 = (tt-16)*64; jbase = j0;
    #pragma unroll
    for (int it=0; it<16; ++it){
      int idx = it*256+t; int r = idx>>6, c = idx&63;
      tile[r][c] = skv[((size_t)b*1024 + 512 + j0 + r)*512 + h*64 + c];
    }
  }
  __syncthreads();
  #pragma unroll
  for (int it=0; it<16; ++it){
    int idx = it*256+t; int c = idx>>6, r = idx&63;
    VT[((size_t)bh*64 + c)*1536 + jbase + r] = tile[r][c];
  }
}

// ---------------- flash attention: staged K/V in LDS, double-buffered (T3 2-phase) ----------------
// grid: 1536 = bh(32) * qgroup(16 of 64 rows) * split(3); 4 waves, each 16 q-rows.
// Swapped MFMA: St = K·Q^T so lane (grp,l16) holds 16 tile-scores for q-row i0+l16.
// K/V tiles staged cooperatively via global_load_lds with XOR swizzle; block-uniform trip count.
__global__ __launch_bounds__(256,2) void attn_k(const u16* __restrict__ Qh, const u16* __restrict__ KEYS,
                                                const u16* __restrict__ VT,
                                                float* __restrict__ Op, float2* __restrict__ Ml2){
  __shared__ alignas(16) u16 Ks[2][64*64];      // 16KB: keys x d, swizzled rows
  __shared__ alignas(16) u16 Vs[2][64*64];      // 16KB: d x keys, swizzled rows
  __shared__ alignas(16) u16 Pl[4][16*64];      // 8KB wave-private P / transpose scratch
  const int t = threadIdx.x, w = t>>6, l = t&63, grp = l>>4, l16 = l&15;
  const int blk = blockIdx.x;
  const int s = blk % 3, qg = (blk/3) & 15, bh = blk/48;
  const int i0 = qg*64 + w*16;
  const int klo = s*512;
  const int cap = klo + 512;
  int khi_blk = qg*64 + 576; if (khi_blk > cap) khi_blk = cap;
  const size_t prow = ((size_t)s*32 + bh)*1024;

  if (khi_blk <= klo){                           // whole block masked
    if (l < 16) Ml2[prow + i0 + l] = make_float2(-1e30f, 0.f);
    return;
  }
  const int nt = (khi_blk - klo) >> 6;           // block-uniform tile count (multiple of 64 range)

  const u16* Qb = Qh + (size_t)bh*65536;
  const u16* Kb = KEYS + (size_t)bh*98304;
  const u16* Vb = VT + (size_t)bh*98304;
  u16* Pw = &Pl[w][0];
  const int swz = (l16&7)<<4;
  const int qlim = i0 + l16 + 512;               // lane's causal bound (key <= qlim)

  bf16v8 qf[2];
  #pragma unroll
  for (int kk=0;kk<2;++kk)
    qf[kk] = *(const bf16v8*)(Qb + (size_t)(i0 + l16)*64 + kk*32 + grp*8);

  f32x4 Ot[4];
  #pragma unroll
  for (int n=0;n<4;++n) Ot[n] = f32x4{0.f,0.f,0.f,0.f};
  float mrun = -1e30f, lrun = 0.f;

  // stage tile 0 into buffer 0 (pre-swizzled source, linear LDS dest; rule #21)
  #pragma unroll
  for (int it=0; it<2; ++it){
    int p16 = it*256 + t; int row = p16>>3; int sb = ((p16&7)<<4) ^ ((row&7)<<4);
    GLDS16(Kb + (size_t)(klo+row)*64 + (sb>>1), &Ks[0][0] + (it*256 + w*64)*8);
    GLDS16(Vb + (size_t)row*1536 + klo + (sb>>1), &Vs[0][0] + (it*256 + w*64)*8);
  }
  __syncthreads();

  for (int tt = 0; tt < nt; ++tt){
    const int j0 = klo + tt*64;
    if (tt+1 < nt){                              // issue next-tile staging, no wait (T3)
      const int j1 = j0 + 64, c1 = (tt+1)&1;
      #pragma unroll
      for (int it=0; it<2; ++it){
        int p16 = it*256 + t; int row = p16>>3; int sb = ((p16&7)<<4) ^ ((row&7)<<4);
        GLDS16(Kb + (size_t)(j1+row)*64 + (sb>>1), &Ks[c1][0] + (it*256 + w*64)*8);
        GLDS16(Vb + (size_t)row*1536 + j1 + (sb>>1), &Vs[c1][0] + (it*256 + w*64)*8);
      }
    }
    const int c = tt&1;
    const char* Kt = (const char*)&Ks[c][0];
    const char* Vt = (const char*)&Vs[c][0];

    f32x4 St[4];
    #pragma unroll
    for (int n=0;n<4;++n) St[n] = f32x4{0.f,0.f,0.f,0.f};
    #pragma unroll
    for (int kk=0;kk<2;++kk)
      #pragma unroll
      for (int n=0;n<4;++n){
        int row = n*16 + l16;
        bf16v8 kf = *(const bf16v8*)(Kt + row*128 + ((kk*64 + grp*16) ^ swz));
        St[n] = mfma16(kf, qf[kk], St[n]);       // swapped: row=key(grp*4+r), col=q(l16)
      }
    const bool tail = (j0 + 63 > i0 + 512);
    float sv[4][4]; float m_loc = -1e30f;
    #pragma unroll
    for (int n=0;n<4;++n)
      #pragma unroll
      for (int r=0;r<4;++r){
        float x = St[n][r];                      // scale folded into Q
        if (tail && (j0 + n*16 + grp*4 + r > qlim)) x = -1e30f;
        sv[n][r] = x; m_loc = fmaxf(m_loc, x);
      }
    m_loc = fmaxf(m_loc, __shfl_xor(m_loc, 16, 64));
    m_loc = fmaxf(m_loc, __shfl_xor(m_loc, 32, 64));
    float mnew = fmaxf(mrun, m_loc);
    float alpha = __expf(mrun - mnew);
    float rs = 0.f;
    unsigned pk[8];
    #pragma unroll
    for (int n=0;n<4;++n)
      #pragma unroll
      for (int c2=0;c2<2;++c2){
        float p0 = __expf(sv[n][2*c2]   - mnew);
        float p1 = __expf(sv[n][2*c2+1] - mnew);
        rs += p0 + p1;
        pk[n*2+c2] = (unsigned)f2b(p0) | ((unsigned)f2b(p1) << 16);
      }
    rs += __shfl_xor(rs, 16, 64);
    rs += __shfl_xor(rs, 32, 64);
    lrun = lrun*alpha + rs;
    mrun = mnew;
    #pragma unroll
    for (int n=0;n<4;++n)
      #pragma unroll
      for (int r=0;r<4;++r) Ot[n][r] *= alpha;
    // P^T -> LDS (bf16 pairs), wave-private, plain ops (same-wave DS is in-order)
    #pragma unroll
    for (int n=0;n<4;++n)
      #pragma unroll
      for (int c2=0;c2<2;++c2)
        *(unsigned*)((char*)Pw + l16*128 + ((n*32 + grp*8 + c2*4) ^ swz)) = pk[n*2+c2];
    bf16v8 pb0 = *(const bf16v8*)((const char*)Pw + l16*128 + ((grp*16)      ^ swz));
    bf16v8 pb1 = *(const bf16v8*)((const char*)Pw + l16*128 + ((64 + grp*16) ^ swz));
    #pragma unroll
    for (int n=0;n<4;++n){
      int row = n*16 + l16;
      bf16v8 vf0 = *(const bf16v8*)(Vt + row*128 + ((grp*16)      ^ swz));
      bf16v8 vf1 = *(const bf16v8*)(Vt + row*128 + ((64 + grp*16) ^ swz));
      Ot[n] = mfma16(vf0, pb0, Ot[n]);
      Ot[n] = mfma16(vf1, pb1, Ot[n]);
    }
    __syncthreads();                             // drains prefetch + guards buffer reuse
  }

  // transpose O^T -> Op[q][d] via per-wave LDS (two 32-d halves), then store
  float* Tw = (float*)Pw;
  #pragma unroll
  for (int hf=0; hf<2; ++hf){
    #pragma unroll
    for (int nn=0; nn<2; ++nn)
      #pragma unroll
      for (int r=0; r<4; ++r)
        *(float*)((char*)Tw + l16*128 + ((((nn*16 + grp*4 + r)*4)) ^ swz)) = Ot[hf*2+nn][r];
    f32x4 v0 = *(const f32x4*)((const char*)Tw + l16*128 + ((grp*32)      ^ swz));
    f32x4 v1 = *(const f32x4*)((const char*)Tw + l16*128 + ((grp*32 + 16) ^ swz));
    float* dst = Op + (prow + i0 + l16)*64 + hf*32 + grp*8;
    *(f32x4*)dst = v0;
    *(f32x4*)(dst+4) = v1;
  }
  if (grp == 0) Ml2[prow + i0 + l16] = make_float2(mrun, lrun);
}

// ---------------- combine 3 KV-split partials -> AO bf16 ----------------
__global__ __launch_bounds__(256) void attn_combine(const float* __restrict__ Op, const float2* __restrict__ Ml2,
                                                    u16* __restrict__ AO){
  int bi = blockIdx.x;                 // b*1024 + i
  int b = bi>>10, i = bi&1023;
  int t = threadIdx.x; int h = t>>6, d = t&63;
  int bh = b*8 + h;
  float2 ml[3]; float M = -1e30f;
  #pragma unroll
  for (int s=0;s<3;++s){ ml[s] = Ml2[((size_t)s*32 + bh)*1024 + i]; M = fmaxf(M, ml[s].x); }
  float denom = 0.f, o = 0.f;
  #pragma unroll
  for (int s=0;s<3;++s){
    if (ml[s].y > 0.f){
      float a = __expf(ml[s].x - M);
      denom += a * ml[s].y;
      o += a * Op[(((size_t)s*32 + bh)*1024 + i)*64 + d];
    }
  }
  AO[((size_t)b*1024 + i)*512 + h*64 + d] = f2b(o / denom);
}

// ---------------- launcher ----------------
extern "C" void kernel_launch(void* const* d_in, const int* in_sizes, int n_in,
                              void* d_out, int out_size, void* d_ws, size_t ws_size,
                              hipStream_t stream) {
  const float* planning = (const float*)d_in[0];
  const float* vk   = (const float*)d_in[1];
  const float* vv   = (const float*)d_in[2];
  const float* Wskv = (const float*)d_in[3];
  const float* bskv = (const float*)d_in[4];
  const float* Wqkv = (const float*)d_in[5];
  const float* bqkv = (const float*)d_in[6];
  const float* Wout = (const float*)d_in[7];
  const float* bout = (const float*)d_in[8];
  const float* Wff1 = (const float*)d_in[9];
  const float* bff1 = (const float*)d_in[10];
  const float* Wff2 = (const float*)d_in[11];
  const float* bff2 = (const float*)d_in[12];
  const float* g1   = (const float*)d_in[13];
  const float* g2   = (const float*)d_in[14];
  float* outp = (float*)d_out;

  char* w8 = (char*)d_ws;
  size_t off = 0;
  auto take = [&](size_t n)->char*{ char* p = w8 + off; off += (n + 255) & ~(size_t)255; return p; };
  u16* vkc     = (u16*)take((size_t)4*512*4096*2);
  u16* vvc     = (u16*)take((size_t)4*512*4096*2);
  u16* WTqkv   = (u16*)take((size_t)1536*512*2);
  u16* WTskv   = (u16*)take((size_t)512*4096*2);
  u16* WTout   = (u16*)take((size_t)512*512*2);
  u16* WTff1   = (u16*)take((size_t)512*512*2);
  u16* WTff2   = (u16*)take((size_t)512*512*2);
  u16* normed1 = (u16*)take((size_t)4096*512*2);
  u16* qkv     = (u16*)take((size_t)4096*1536*2);
  u16* skv     = (u16*)take((size_t)4096*512*2);
  u16* Qh      = (u16*)take((size_t)32*1024*64*2);
  u16* KEYS    = (u16*)take((size_t)32*1536*64*2);
  u16* VT      = (u16*)take((size_t)32*64*1536*2);
  u16* AO      = (u16*)take((size_t)4096*512*2);
  float* all_out = (float*)take((size_t)4096*512*4);
  u16* normed2 = (u16*)take((size_t)4096*512*2);
  u16* h1      = (u16*)take((size_t)4096*512*2);
  float* Op    = (float*)take((size_t)3*32*1024*64*4);
  float2* Ml2  = (float2*)take((size_t)3*32*1024*8);
  (void)in_sizes; (void)n_in; (void)out_size; (void)ws_size;

  convert_k<<<dim3(4096), 256, 0, stream>>>(vk, vkc, 1048576);
  convert_k<<<dim3(4096), 256, 0, stream>>>(vv, vvc, 1048576);

  transpose_k<<<dim3(192), 256, 0, stream>>>(Wqkv, WTqkv, 512, 1536);
  transpose_k<<<dim3(512), 256, 0, stream>>>(Wskv, WTskv, 4096, 512);
  transpose_k<<<dim3(64),  256, 0, stream>>>(Wout, WTout, 512, 512);
  transpose_k<<<dim3(64),  256, 0, stream>>>(Wff1, WTff1, 512, 512);
  transpose_k<<<dim3(64),  256, 0, stream>>>(Wff2, WTff2, 512, 512);
  rmsn_k<<<dim3(1024), 256, 0, stream>>>(planning, g1, normed1);

  gemm_k<128,0,false><<<dim3(12,32), 256, 0, stream>>>(normed1,nullptr,nullptr, WTqkv, bqkv, qkv, nullptr, nullptr, nullptr, 4096, 1536, 512);
  gemm_k<64,0,true ><<<dim3(8,32),  256, 0, stream>>>(nullptr, vkc, vvc,       WTskv, bskv, skv, nullptr, nullptr, nullptr, 4096, 512, 4096);

  scatter_qk<<<dim3(4096), 256, 0, stream>>>(qkv, skv, Qh, KEYS);
  build_vt<<<dim3(768), 256, 0, stream>>>(qkv, skv, VT);

  attn_k<<<dim3(1536), 256, 0, stream>>>(Qh, KEYS, VT, Op, Ml2);
  attn_combine<<<dim3(4096), 256, 0, stream>>>(Op, Ml2, AO);

  gemm_k<64,1,false><<<dim3(8,32), 256, 0, stream>>>(AO, nullptr,nullptr, WTout, bout, nullptr, all_out, planning, nullptr, 4096, 512, 512);
  rmsn_k<<<dim3(1024), 256, 0, stream>>>(all_out, g2, normed2);
  gemm_k<64,2,false><<<dim3(8,32), 256, 0, stream>>>(normed2, nullptr,nullptr, WTff1, bff1, h1, nullptr, nullptr, nullptr, 4096, 512, 512);
  gemm_k<64,3,false><<<dim3(8,32), 256, 0, stream>>>(h1, nullptr,nullptr, WTff2, bff2, nullptr, outp, nullptr, all_out, 4096, 512, 512);
}

// Round 8
// 174.731 us; speedup vs baseline: 1.4877x; 1.1685x over previous
//
#include <hip/hip_runtime.h>
#include <math.h>

typedef unsigned short u16;
typedef unsigned short u16x8 __attribute__((ext_vector_type(8)));
typedef __bf16 bf16v8 __attribute__((ext_vector_type(8)));
typedef float f32x4 __attribute__((ext_vector_type(4)));

static __device__ __forceinline__ float b2f(u16 u){ union{unsigned v; float f;} x; x.v=((unsigned)u)<<16; return x.f; }
static __device__ __forceinline__ u16 f2b(float f){ union{float f; unsigned v;} x; x.f=f; unsigned r=x.v+0x7fffu+((x.v>>16)&1u); return (u16)(r>>16); }
static __device__ __forceinline__ f32x4 mfma16(bf16v8 a, bf16v8 b, f32x4 c){
  return __builtin_amdgcn_mfma_f32_16x16x32_bf16(a,b,c,0,0,0);
}
#define GLDS16(g,l) __builtin_amdgcn_global_load_lds((const __attribute__((address_space(1))) unsigned*)(g), (__attribute__((address_space(3))) unsigned*)(l), 16, 0, 0)

// ---------------- convert f32 -> bf16 ----------------
__global__ __launch_bounds__(256) void convert_k(const float* __restrict__ src, u16* __restrict__ dst, int n8){
  int i = blockIdx.x*256 + threadIdx.x;
  if (i >= n8) return;
  const float* s = src + (size_t)i*8;
  f32x4 a = *(const f32x4*)s, b = *(const f32x4*)(s+4);
  u16x8 o;
  #pragma unroll
  for (int j=0;j<4;++j){ o[j] = f2b(a[j]); o[j+4] = f2b(b[j]); }
  *(u16x8*)(dst + (size_t)i*8) = o;
}

// ---------------- weight transpose: f32 in [R][C] -> bf16 out [C][R] ----------------
__global__ __launch_bounds__(256) void transpose_k(const float* __restrict__ in, u16* __restrict__ out, int R, int C){
  __shared__ u16 tile[64][66];
  int ct = C >> 6;
  int bx = blockIdx.x % ct, by = blockIdx.x / ct;
  int t = threadIdx.x;
  #pragma unroll
  for (int it=0; it<16; ++it){
    int idx = it*256 + t; int r = idx>>6, c = idx&63;
    tile[r][c] = f2b(in[(size_t)(by*64+r)*C + bx*64 + c]);
  }
  __syncthreads();
  #pragma unroll
  for (int it=0; it<16; ++it){
    int idx = it*256 + t; int c = idx>>6, r = idx&63;
    out[(size_t)(bx*64+c)*R + by*64 + r] = tile[r][c];
  }
}

// ---------------- rmsnorm: f32 in, f32 gamma, bf16 out ----------------
__global__ __launch_bounds__(256) void rmsn_k(const float* __restrict__ x, const float* __restrict__ g, u16* __restrict__ o){
  int w = threadIdx.x>>6, l = threadIdx.x&63;
  size_t row = (size_t)blockIdx.x*4 + w;
  const float* xr = x + row*512 + l*8;
  f32x4 a = *(const f32x4*)xr, b = *(const f32x4*)(xr+4);
  float f[8]; float ss = 0.f;
  #pragma unroll
  for (int j=0;j<4;++j){ f[j]=a[j]; f[j+4]=b[j]; }
  #pragma unroll
  for (int j=0;j<8;++j) ss += f[j]*f[j];
  #pragma unroll
  for (int m=1;m<64;m<<=1) ss += __shfl_xor(ss, m, 64);
  float inv = rsqrtf(ss*(1.0f/512.f) + 1e-6f);
  f32x4 ga = *(const f32x4*)(g + l*8), gb = *(const f32x4*)(g + l*8 + 4);
  u16x8 ov;
  #pragma unroll
  for (int j=0;j<4;++j){ ov[j] = f2b(f[j]*inv*(1.f + ga[j])); ov[j+4] = f2b(f[j+4]*inv*(1.f + gb[j])); }
  *(u16x8*)(o + row*512 + l*8) = ov;
}

// ---------------- GEMM: C[M,N] = A[M,K] @ BT[N,K]^T + bias, epilogues ----------------
// grid: (x = m-tile, y = n-tile, z = k-split). x-fastest dispatch puts blocks sharing
// an A-panel {x + nx*y} on the SAME XCD (nx multiple of 8 keeps x%8 = XCD id) -> L2 reuse.
// SPLITS>1: write f32 partial (no bias) to Cf[z*M*N + row*N + col]; combine kernel finishes.
// EPI 0: bias -> bf16 Cb ; 1: bias+resid -> f32 Cf ; 2: bias+gelu -> bf16 Cb ; 3: bias+addf -> f32 Cf
template<int BN, int EPI, bool CONCAT, int SPLITS>
__global__ __launch_bounds__(256,2) void gemm_k(
  const u16* __restrict__ A, const u16* __restrict__ Avk, const u16* __restrict__ Avv,
  const u16* __restrict__ BT, const float* __restrict__ bias,
  u16* __restrict__ Cb, float* __restrict__ Cf,
  const float* __restrict__ resid, const float* __restrict__ addf,
  int M, int N, int K)
{
  constexpr int BM = 128, BK = 64;
  constexpr int NFR = BN/32;
  __shared__ alignas(16) u16 sm[(BM+BN)*BK];
  u16* As = sm; u16* Bs = sm + BM*BK;
  const int t = threadIdx.x, w = t>>6, l = t&63, grp = l>>4, l16 = l&15;
  const int wr = w>>1, wc = w&1;
  const int m0 = blockIdx.x*BM, n0 = blockIdx.y*BN;
  const int kchunk = K/SPLITS, kbeg = blockIdx.z*kchunk, kend = kbeg + kchunk;

  f32x4 acc[4][NFR];
  #pragma unroll
  for (int m=0;m<4;++m)
    #pragma unroll
    for (int n=0;n<NFR;++n) acc[m][n] = f32x4{0.f,0.f,0.f,0.f};

  for (int k0 = kbeg; k0 < kend; k0 += BK){
    #pragma unroll
    for (int it=0; it<4; ++it){
      int p16 = it*256 + t;
      int row = p16>>3; int offb = (p16&7)<<4;
      int swz = offb ^ ((row&7)<<4);
      const u16* src;
      if (CONCAT){
        int g = m0+row, bb = g>>10, ii = g&1023;
        const u16* base = (ii < 512) ? (Avk + (size_t)(bb*512+ii)*4096)
                                     : (Avv + (size_t)(bb*512+ii-512)*4096);
        src = base + k0 + (swz>>1);
      } else {
        src = A + (size_t)(m0+row)*K + k0 + (swz>>1);
      }
      GLDS16(src, As + (it*256 + w*64)*8);
    }
    #pragma unroll
    for (int it=0; it<NFR; ++it){
      int p16 = it*256 + t;
      int row = p16>>3; int offb = (p16&7)<<4;
      int swz = offb ^ ((row&7)<<4);
      const u16* src = BT + (size_t)(n0+row)*K + k0 + (swz>>1);
      GLDS16(src, Bs + (it*256 + w*64)*8);
    }
    __syncthreads();

    bf16v8 af[4][2], bfr[NFR][2];
    #pragma unroll
    for (int kk=0;kk<2;++kk){
      #pragma unroll
      for (int m=0;m<4;++m){
        int row = wr*64 + m*16 + l16;
        int offb = (kk*64 + grp*16) ^ ((row&7)<<4);
        af[m][kk] = *(const bf16v8*)((const char*)As + row*128 + offb);
      }
      #pragma unroll
      for (int n=0;n<NFR;++n){
        int row = wc*(BN/2) + n*16 + l16;
        int offb = (kk*64 + grp*16) ^ ((row&7)<<4);
        bfr[n][kk] = *(const bf16v8*)((const char*)Bs + row*128 + offb);
      }
    }
    #pragma unroll
    for (int kk=0;kk<2;++kk)
      #pragma unroll
      for (int m=0;m<4;++m)
        #pragma unroll
        for (int n=0;n<NFR;++n)
          acc[m][n] = mfma16(af[m][kk], bfr[n][kk], acc[m][n]);
    __syncthreads();
  }

  #pragma unroll
  for (int m=0;m<4;++m){
    #pragma unroll
    for (int n=0;n<NFR;++n){
      #pragma unroll
      for (int r=0;r<4;++r){
        int row = m0 + wr*64 + m*16 + grp*4 + r;
        int col = n0 + wc*(BN/2) + n*16 + l16;
        size_t idx = (size_t)row*N + col;
        if (SPLITS > 1){
          Cf[(size_t)blockIdx.z*M*N + idx] = acc[m][n][r];
        } else {
          float v = acc[m][n][r] + bias[col];
          if (EPI == 0){
            Cb[idx] = f2b(v);
          } else if (EPI == 1){
            Cf[idx] = v + resid[idx];
          } else if (EPI == 2){
            v = 0.5f*v*(1.f + erff(v*0.70710678f));
            Cb[idx] = f2b(v);
          } else {
            Cf[idx] = v + addf[idx];
          }
        }
      }
    }
  }
}

// ---------------- split-K combine: sum 4 partials + bias -> bf16 ----------------
__global__ __launch_bounds__(256) void splitk_combine(const float* __restrict__ P, const float* __restrict__ bias,
                                                      u16* __restrict__ out, int n8, int N){
  int i = blockIdx.x*256 + threadIdx.x;
  if (i >= n8) return;
  size_t base = (size_t)i*8;
  const size_t MN = (size_t)n8*8;
  float acc[8];
  {
    f32x4 a = *(const f32x4*)(P + base), b = *(const f32x4*)(P + base + 4);
    #pragma unroll
    for (int j=0;j<4;++j){ acc[j]=a[j]; acc[j+4]=b[j]; }
  }
  #pragma unroll
  for (int s=1;s<4;++s){
    f32x4 a = *(const f32x4*)(P + s*MN + base), b = *(const f32x4*)(P + s*MN + base + 4);
    #pragma unroll
    for (int j=0;j<4;++j){ acc[j]+=a[j]; acc[j+4]+=b[j]; }
  }
  int col0 = (int)(base % N);
  u16x8 o;
  #pragma unroll
  for (int j=0;j<8;++j) o[j] = f2b(acc[j] + bias[col0+j]);
  *(u16x8*)(out + base) = o;
}

// ---------------- scatter q/k with rope (q pre-scaled by 1/8); copy sk into KEYS ----------------
__global__ __launch_bounds__(256) void scatter_qk(const u16* __restrict__ qkv, const u16* __restrict__ skv,
                                                  u16* __restrict__ Qh, u16* __restrict__ KEYS){
  int bi = blockIdx.x;             // row = b*1024 + i
  int b = bi>>10, i = bi&1023;
  int t = threadIdx.x;
  int h = t>>5, dp = t&31;
  const u16* qrow = qkv + (size_t)bi*1536;
  float invf = __expf(-(float)dp * (9.2103403720f/32.f));  // 10000^(-dp/32)
  float fr = (float)i * invf;
  float sn, cs; __sincosf(fr, &sn, &cs);
  int bh = b*8 + h;
  float x1 = b2f(qrow[h*64+dp]), x2 = b2f(qrow[h*64+dp+32]);
  u16* qd = Qh + ((size_t)bh*1024 + i)*64;
  qd[dp]    = f2b((x1*cs - x2*sn)*0.125f);
  qd[dp+32] = f2b((x2*cs + x1*sn)*0.125f);
  x1 = b2f(qrow[512+h*64+dp]); x2 = b2f(qrow[512+h*64+dp+32]);
  u16* kd = KEYS + ((size_t)bh*1536 + 512 + i)*64;
  kd[dp]    = f2b(x1*cs - x2*sn);
  kd[dp+32] = f2b(x2*cs + x1*sn);
  if (i < 512){
    const u16* skrow = skv + ((size_t)b*1024 + i)*512;
    for (int e = t; e < 512; e += 256){
      int hh = e>>6, d = e&63;
      KEYS[((size_t)(b*8+hh)*1536 + i)*64 + d] = skrow[e];
    }
  }
}

// ---------------- build transposed values VT[bh][d][j] ----------------
__global__ __launch_bounds__(256) void build_vt(const u16* __restrict__ qkv, const u16* __restrict__ skv,
                                                u16* __restrict__ VT){
  __shared__ u16 tile[64][66];
  int blk = blockIdx.x;
  int bh = blk / 24, tt = blk % 24;
  int b = bh>>3, h = bh&7;
  int t = threadIdx.x;
  int jbase;
  if (tt < 16){
    int i0 = tt*64; jbase = 512 + i0;
    #pragma unroll
    for (int it=0; it<16; ++it){
      int idx = it*256+t; int r = idx>>6, c = idx&63;
      tile[r][c] = qkv[((size_t)b*1024 + i0 + r)*1536 + 1024 + h*64 + c];
    }
  } else {
    int j0 = (tt-16)*64; jbase = j0;
    #pragma unroll
    for (int it=0; it<16; ++it){
      int idx = it*256+t; int r = idx>>6, c = idx&63;
      tile[r][c] = skv[((size_t)b*1024 + 512 + j0 + r)*512 + h*64 + c];
    }
  }
  __syncthreads();
  #pragma unroll
  for (int it=0; it<16; ++it){
    int idx = it*256+t; int c = idx>>6, r = idx&63;
    VT[((size_t)bh*64 + c)*1536 + jbase + r] = tile[r][c];
  }
}

// ---------------- flash attention: staged K/V in LDS, double-buffered (T3 2-phase) ----------------
__global__ __launch_bounds__(256,2) void attn_k(const u16* __restrict__ Qh, const u16* __restrict__ KEYS,
                                                const u16* __restrict__ VT,
                                                float* __restrict__ Op, float2* __restrict__ Ml2){
  __shared__ alignas(16) u16 Ks[2][64*64];
  __shared__ alignas(16) u16 Vs[2][64*64];
  __shared__ alignas(16) u16 Pl[4][16*64];
  const int t = threadIdx.x, w = t>>6, l = t&63, grp = l>>4, l16 = l&15;
  const int blk = blockIdx.x;
  const int s = blk % 3, qg = (blk/3) & 15, bh = blk/48;
  const int i0 = qg*64 + w*16;
  const int klo = s*512;
  const int cap = klo + 512;
  int khi_blk = qg*64 + 576; if (khi_blk > cap) khi_blk = cap;
  const size_t prow = ((size_t)s*32 + bh)*1024;

  if (khi_blk <= klo){
    if (l < 16) Ml2[prow + i0 + l] = make_float2(-1e30f, 0.f);
    return;
  }
  const int nt = (khi_blk - klo) >> 6;

  const u16* Qb = Qh + (size_t)bh*65536;
  const u16* Kb = KEYS + (size_t)bh*98304;
  const u16* Vb = VT + (size_t)bh*98304;
  u16* Pw = &Pl[w][0];
  const int swz = (l16&7)<<4;
  const int qlim = i0 + l16 + 512;

  bf16v8 qf[2];
  #pragma unroll
  for (int kk=0;kk<2;++kk)
    qf[kk] = *(const bf16v8*)(Qb + (size_t)(i0 + l16)*64 + kk*32 + grp*8);

  f32x4 Ot[4];
  #pragma unroll
  for (int n=0;n<4;++n) Ot[n] = f32x4{0.f,0.f,0.f,0.f};
  float mrun = -1e30f, lrun = 0.f;

  #pragma unroll
  for (int it=0; it<2; ++it){
    int p16 = it*256 + t; int row = p16>>3; int sb = ((p16&7)<<4) ^ ((row&7)<<4);
    GLDS16(Kb + (size_t)(klo+row)*64 + (sb>>1), &Ks[0][0] + (it*256 + w*64)*8);
    GLDS16(Vb + (size_t)row*1536 + klo + (sb>>1), &Vs[0][0] + (it*256 + w*64)*8);
  }
  __syncthreads();

  for (int tt = 0; tt < nt; ++tt){
    const int j0 = klo + tt*64;
    if (tt+1 < nt){
      const int j1 = j0 + 64, c1 = (tt+1)&1;
      #pragma unroll
      for (int it=0; it<2; ++it){
        int p16 = it*256 + t; int row = p16>>3; int sb = ((p16&7)<<4) ^ ((row&7)<<4);
        GLDS16(Kb + (size_t)(j1+row)*64 + (sb>>1), &Ks[c1][0] + (it*256 + w*64)*8);
        GLDS16(Vb + (size_t)row*1536 + j1 + (sb>>1), &Vs[c1][0] + (it*256 + w*64)*8);
      }
    }
    const int c = tt&1;
    const char* Kt = (const char*)&Ks[c][0];
    const char* Vt = (const char*)&Vs[c][0];

    f32x4 St[4];
    #pragma unroll
    for (int n=0;n<4;++n) St[n] = f32x4{0.f,0.f,0.f,0.f};
    #pragma unroll
    for (int kk=0;kk<2;++kk)
      #pragma unroll
      for (int n=0;n<4;++n){
        int row = n*16 + l16;
        bf16v8 kf = *(const bf16v8*)(Kt + row*128 + ((kk*64 + grp*16) ^ swz));
        St[n] = mfma16(kf, qf[kk], St[n]);
      }
    const bool tail = (j0 + 63 > i0 + 512);
    float sv[4][4]; float m_loc = -1e30f;
    #pragma unroll
    for (int n=0;n<4;++n)
      #pragma unroll
      for (int r=0;r<4;++r){
        float x = St[n][r];
        if (tail && (j0 + n*16 + grp*4 + r > qlim)) x = -1e30f;
        sv[n][r] = x; m_loc = fmaxf(m_loc, x);
      }
    m_loc = fmaxf(m_loc, __shfl_xor(m_loc, 16, 64));
    m_loc = fmaxf(m_loc, __shfl_xor(m_loc, 32, 64));
    float mnew = fmaxf(mrun, m_loc);
    float alpha = __expf(mrun - mnew);
    float rs = 0.f;
    unsigned pk[8];
    #pragma unroll
    for (int n=0;n<4;++n)
      #pragma unroll
      for (int c2=0;c2<2;++c2){
        float p0 = __expf(sv[n][2*c2]   - mnew);
        float p1 = __expf(sv[n][2*c2+1] - mnew);
        rs += p0 + p1;
        pk[n*2+c2] = (unsigned)f2b(p0) | ((unsigned)f2b(p1) << 16);
      }
    rs += __shfl_xor(rs, 16, 64);
    rs += __shfl_xor(rs, 32, 64);
    lrun = lrun*alpha + rs;
    mrun = mnew;
    #pragma unroll
    for (int n=0;n<4;++n)
      #pragma unroll
      for (int r=0;r<4;++r) Ot[n][r] *= alpha;
    #pragma unroll
    for (int n=0;n<4;++n)
      #pragma unroll
      for (int c2=0;c2<2;++c2)
        *(unsigned*)((char*)Pw + l16*128 + ((n*32 + grp*8 + c2*4) ^ swz)) = pk[n*2+c2];
    bf16v8 pb0 = *(const bf16v8*)((const char*)Pw + l16*128 + ((grp*16)      ^ swz));
    bf16v8 pb1 = *(const bf16v8*)((const char*)Pw + l16*128 + ((64 + grp*16) ^ swz));
    #pragma unroll
    for (int n=0;n<4;++n){
      int row = n*16 + l16;
      bf16v8 vf0 = *(const bf16v8*)(Vt + row*128 + ((grp*16)      ^ swz));
      bf16v8 vf1 = *(const bf16v8*)(Vt + row*128 + ((64 + grp*16) ^ swz));
      Ot[n] = mfma16(vf0, pb0, Ot[n]);
      Ot[n] = mfma16(vf1, pb1, Ot[n]);
    }
    __syncthreads();
  }

  float* Tw = (float*)Pw;
  #pragma unroll
  for (int hf=0; hf<2; ++hf){
    #pragma unroll
    for (int nn=0; nn<2; ++nn)
      #pragma unroll
      for (int r=0; r<4; ++r)
        *(float*)((char*)Tw + l16*128 + ((((nn*16 + grp*4 + r)*4)) ^ swz)) = Ot[hf*2+nn][r];
    f32x4 v0 = *(const f32x4*)((const char*)Tw + l16*128 + ((grp*32)      ^ swz));
    f32x4 v1 = *(const f32x4*)((const char*)Tw + l16*128 + ((grp*32 + 16) ^ swz));
    float* dst = Op + (prow + i0 + l16)*64 + hf*32 + grp*8;
    *(f32x4*)dst = v0;
    *(f32x4*)(dst+4) = v1;
  }
  if (grp == 0) Ml2[prow + i0 + l16] = make_float2(mrun, lrun);
}

// ---------------- combine 3 KV-split partials -> AO bf16 ----------------
__global__ __launch_bounds__(256) void attn_combine(const float* __restrict__ Op, const float2* __restrict__ Ml2,
                                                    u16* __restrict__ AO){
  int bi = blockIdx.x;                 // b*1024 + i
  int b = bi>>10, i = bi&1023;
  int t = threadIdx.x; int h = t>>6, d = t&63;
  int bh = b*8 + h;
  float2 ml[3]; float M = -1e30f;
  #pragma unroll
  for (int s=0;s<3;++s){ ml[s] = Ml2[((size_t)s*32 + bh)*1024 + i]; M = fmaxf(M, ml[s].x); }
  float denom = 0.f, o = 0.f;
  #pragma unroll
  for (int s=0;s<3;++s){
    if (ml[s].y > 0.f){
      float a = __expf(ml[s].x - M);
      denom += a * ml[s].y;
      o += a * Op[(((size_t)s*32 + bh)*1024 + i)*64 + d];
    }
  }
  AO[((size_t)b*1024 + i)*512 + h*64 + d] = f2b(o / denom);
}

// ---------------- launcher ----------------
extern "C" void kernel_launch(void* const* d_in, const int* in_sizes, int n_in,
                              void* d_out, int out_size, void* d_ws, size_t ws_size,
                              hipStream_t stream) {
  const float* planning = (const float*)d_in[0];
  const float* vk   = (const float*)d_in[1];
  const float* vv   = (const float*)d_in[2];
  const float* Wskv = (const float*)d_in[3];
  const float* bskv = (const float*)d_in[4];
  const float* Wqkv = (const float*)d_in[5];
  const float* bqkv = (const float*)d_in[6];
  const float* Wout = (const float*)d_in[7];
  const float* bout = (const float*)d_in[8];
  const float* Wff1 = (const float*)d_in[9];
  const float* bff1 = (const float*)d_in[10];
  const float* Wff2 = (const float*)d_in[11];
  const float* bff2 = (const float*)d_in[12];
  const float* g1   = (const float*)d_in[13];
  const float* g2   = (const float*)d_in[14];
  float* outp = (float*)d_out;

  char* w8 = (char*)d_ws;
  size_t off = 0;
  auto take = [&](size_t n)->char*{ char* p = w8 + off; off += (n + 255) & ~(size_t)255; return p; };
  u16* vkc     = (u16*)take((size_t)4*512*4096*2);
  u16* vvc     = (u16*)take((size_t)4*512*4096*2);
  u16* WTqkv   = (u16*)take((size_t)1536*512*2);
  u16* WTskv   = (u16*)take((size_t)512*4096*2);
  u16* WTout   = (u16*)take((size_t)512*512*2);
  u16* WTff1   = (u16*)take((size_t)512*512*2);
  u16* WTff2   = (u16*)take((size_t)512*512*2);
  u16* normed1 = (u16*)take((size_t)4096*512*2);
  u16* qkv     = (u16*)take((size_t)4096*1536*2);
  u16* skv     = (u16*)take((size_t)4096*512*2);
  u16* Qh      = (u16*)take((size_t)32*1024*64*2);
  u16* KEYS    = (u16*)take((size_t)32*1536*64*2);
  u16* VT      = (u16*)take((size_t)32*64*1536*2);
  u16* AO      = (u16*)take((size_t)4096*512*2);
  float* all_out = (float*)take((size_t)4096*512*4);
  u16* normed2 = (u16*)take((size_t)4096*512*2);
  u16* h1      = (u16*)take((size_t)4096*512*2);
  float* Op    = (float*)take((size_t)3*32*1024*64*4);
  float2* Ml2  = (float2*)take((size_t)3*32*1024*8);
  float* Pd    = (float*)take((size_t)4*4096*512*4);   // split-K partials
  (void)in_sizes; (void)n_in; (void)out_size; (void)ws_size;

  convert_k<<<dim3(4096), 256, 0, stream>>>(vk, vkc, 1048576);
  convert_k<<<dim3(4096), 256, 0, stream>>>(vv, vvc, 1048576);

  transpose_k<<<dim3(192), 256, 0, stream>>>(Wqkv, WTqkv, 512, 1536);
  transpose_k<<<dim3(512), 256, 0, stream>>>(Wskv, WTskv, 4096, 512);
  transpose_k<<<dim3(64),  256, 0, stream>>>(Wout, WTout, 512, 512);
  transpose_k<<<dim3(64),  256, 0, stream>>>(Wff1, WTff1, 512, 512);
  transpose_k<<<dim3(64),  256, 0, stream>>>(Wff2, WTff2, 512, 512);
  rmsn_k<<<dim3(1024), 256, 0, stream>>>(planning, g1, normed1);

  gemm_k<128,0,false,1><<<dim3(32,12), 256, 0, stream>>>(normed1,nullptr,nullptr, WTqkv, bqkv, qkv, nullptr, nullptr, nullptr, 4096, 1536, 512);
  gemm_k<64,0,true, 4><<<dim3(32,8,4), 256, 0, stream>>>(nullptr, vkc, vvc,      WTskv, bskv, nullptr, Pd, nullptr, nullptr, 4096, 512, 4096);
  splitk_combine<<<dim3(1024), 256, 0, stream>>>(Pd, bskv, skv, 262144, 512);

  scatter_qk<<<dim3(4096), 256, 0, stream>>>(qkv, skv, Qh, KEYS);
  build_vt<<<dim3(768), 256, 0, stream>>>(qkv, skv, VT);

  attn_k<<<dim3(1536), 256, 0, stream>>>(Qh, KEYS, VT, Op, Ml2);
  attn_combine<<<dim3(4096), 256, 0, stream>>>(Op, Ml2, AO);

  gemm_k<64,1,false,1><<<dim3(32,8), 256, 0, stream>>>(AO, nullptr,nullptr, WTout, bout, nullptr, all_out, planning, nullptr, 4096, 512, 512);
  rmsn_k<<<dim3(1024), 256, 0, stream>>>(all_out, g2, normed2);
  gemm_k<64,2,false,1><<<dim3(32,8), 256, 0, stream>>>(normed2, nullptr,nullptr, WTff1, bff1, h1, nullptr, nullptr, nullptr, 4096, 512, 512);
  gemm_k<64,3,false,1><<<dim3(32,8), 256, 0, stream>>>(h1, nullptr,nullptr, WTff2, bff2, nullptr, outp, nullptr, all_out, 4096, 512, 512);
}